// Round 1
// baseline (37173.877 us; speedup 1.0000x reference)
//
#include <hip/hip_runtime.h>
#include <math.h>

// Discriminator GRU: B=64, T=1024, S=1024.
// Round 1: correct fp32 baseline.
//   K1: x_gates[B*T][3S] = batch @ W_ih^T + b_ih (+ b_hh for r,z gates)  -> ws
//   K2 x1024: h_{t+1} = GRU(h_t, x_gates[:,t,:])  (one launch per step, dbuf h)
//   K3: out[b] = sigmoid(h_T[b] . W_out + b_out)
// ws layout: [ xg: 64*1024*3072 f32 (768 MB) | hA: 64*1024 f32 | hB: 64*1024 f32 ]

#define BB 64
#define TT 1024
#define SS 1024
#define GG (3 * SS)

// ---------------------------------------------------------------------------
// K1: C[M=B*T][N=3S] = A[M][K=S] * W[N][K]^T + bias(n)
// bias(n) = b_ih[n] + (n < 2S ? b_hh[n] : 0)   (b_hh for n-gate applied in K2)
// 128x128 tile, BK=16, 256 threads, 8x8 microtile.
// ---------------------------------------------------------------------------
__global__ __launch_bounds__(256) void xgates_kernel(
    const float* __restrict__ A, const float* __restrict__ W,
    const float* __restrict__ b_ih, const float* __restrict__ b_hh,
    float* __restrict__ C) {
  __shared__ float As[16][132];  // [k][m], +4 pad: bank = (4k+m)%32
  __shared__ float Bs[16][132];  // [k][n]

  const int tid = threadIdx.x;
  const int n0 = blockIdx.x * 128;  // 24 n-tiles
  const int m0 = blockIdx.y * 128;  // 512 m-tiles
  const int tx = tid & 15;          // n dir
  const int ty = tid >> 4;          // m dir

  float acc[8][8];
#pragma unroll
  for (int i = 0; i < 8; ++i)
#pragma unroll
    for (int j = 0; j < 8; ++j) acc[i][j] = 0.f;

  for (int kt = 0; kt < SS / 16; ++kt) {
    const int k0 = kt * 16;
    // stage A-tile and B-tile: 128 rows x 16 k each; 2 float4 per thread per tile
#pragma unroll
    for (int i = 0; i < 2; ++i) {
      const int idx = tid + i * 256;      // 0..511
      const int r = idx >> 2;             // 0..127
      const int kq = (idx & 3) * 4;       // 0,4,8,12
      float4 av = *(const float4*)&A[(size_t)(m0 + r) * SS + k0 + kq];
      float4 bv = *(const float4*)&W[(size_t)(n0 + r) * SS + k0 + kq];
      As[kq + 0][r] = av.x; As[kq + 1][r] = av.y;
      As[kq + 2][r] = av.z; As[kq + 3][r] = av.w;
      Bs[kq + 0][r] = bv.x; Bs[kq + 1][r] = bv.y;
      Bs[kq + 2][r] = bv.z; Bs[kq + 3][r] = bv.w;
    }
    __syncthreads();
#pragma unroll
    for (int k = 0; k < 16; ++k) {
      float4 a0 = *(const float4*)&As[k][ty * 8];
      float4 a1 = *(const float4*)&As[k][ty * 8 + 4];
      float4 b0 = *(const float4*)&Bs[k][tx * 8];
      float4 b1 = *(const float4*)&Bs[k][tx * 8 + 4];
      float a[8] = {a0.x, a0.y, a0.z, a0.w, a1.x, a1.y, a1.z, a1.w};
      float b[8] = {b0.x, b0.y, b0.z, b0.w, b1.x, b1.y, b1.z, b1.w};
#pragma unroll
      for (int i = 0; i < 8; ++i)
#pragma unroll
        for (int j = 0; j < 8; ++j) acc[i][j] = fmaf(a[i], b[j], acc[i][j]);
    }
    __syncthreads();
  }

  // epilogue: add bias, store
  float bias[8];
#pragma unroll
  for (int j = 0; j < 8; ++j) {
    const int n = n0 + tx * 8 + j;
    bias[j] = b_ih[n] + (n < 2 * SS ? b_hh[n] : 0.f);
  }
#pragma unroll
  for (int i = 0; i < 8; ++i) {
    const size_t row = (size_t)(m0 + ty * 8 + i) * GG + n0 + tx * 8;
    float4 s0 = make_float4(acc[i][0] + bias[0], acc[i][1] + bias[1],
                            acc[i][2] + bias[2], acc[i][3] + bias[3]);
    float4 s1 = make_float4(acc[i][4] + bias[4], acc[i][5] + bias[5],
                            acc[i][6] + bias[6], acc[i][7] + bias[7]);
    *(float4*)&C[row] = s0;
    *(float4*)&C[row + 4] = s1;
  }
}

// ---------------------------------------------------------------------------
// K2: one GRU step. Grid 128 blocks = 4 batch-tiles(16) x 32 unit-tiles(32).
// blockIdx = bt*32 + ut so blockIdx%8 == ut%8: same-unit-tile blocks share an
// XCD -> W_hh slice fetched once per XCD L2 per step (~12 MB/step from L3).
// Thread: unit u = u0 + (tid>>3), batches b0+(tid&7) and b0+(tid&7)+8.
// ---------------------------------------------------------------------------
__global__ __launch_bounds__(256) void gru_step_kernel(
    const float* __restrict__ hprev, float* __restrict__ hnext,
    const float* __restrict__ Whh, const float* __restrict__ xg,
    const float* __restrict__ bhh, const int t) {
  __shared__ float Hs[16][68];  // [b_local][k], +4 pad
  __shared__ float Ws[96][68];  // [gate*32+u_local][k]

  const int tid = threadIdx.x;
  const int ut = blockIdx.x & 31;
  const int bt = blockIdx.x >> 5;
  const int u0 = ut * 32;
  const int b0 = bt * 16;
  const int ul = tid >> 3;  // 0..31
  const int bp = tid & 7;   // 0..7

  const int hr = tid >> 4;         // h staging row 0..15
  const int hkq = (tid & 15) * 4;  // k quad

  float ar[2] = {0.f, 0.f}, az[2] = {0.f, 0.f}, an[2] = {0.f, 0.f};

  for (int kc = 0; kc < 16; ++kc) {
    const int k0 = kc * 64;
    // stage h: 16 x 64 floats
    float4 hv = *(const float4*)&hprev[(size_t)(b0 + hr) * SS + k0 + hkq];
    *(float4*)&Hs[hr][hkq] = hv;
    // stage W: 96 rows x 64 k = 1536 float4, 6 per thread
#pragma unroll
    for (int i = 0; i < 6; ++i) {
      const int idx = tid + i * 256;
      const int r = idx >> 4;          // 0..95
      const int kq = (idx & 15) * 4;
      const int gate = r >> 5;
      const int uu = r & 31;
      float4 wv =
          *(const float4*)&Whh[(size_t)(gate * SS + u0 + uu) * SS + k0 + kq];
      *(float4*)&Ws[r][kq] = wv;
    }
    __syncthreads();
#pragma unroll
    for (int k4 = 0; k4 < 16; ++k4) {
      float4 h0 = *(const float4*)&Hs[bp][k4 * 4];
      float4 h1 = *(const float4*)&Hs[bp + 8][k4 * 4];
      float4 wr = *(const float4*)&Ws[ul][k4 * 4];
      float4 wz = *(const float4*)&Ws[32 + ul][k4 * 4];
      float4 wn = *(const float4*)&Ws[64 + ul][k4 * 4];
      ar[0] = fmaf(h0.x, wr.x, fmaf(h0.y, wr.y, fmaf(h0.z, wr.z, fmaf(h0.w, wr.w, ar[0]))));
      az[0] = fmaf(h0.x, wz.x, fmaf(h0.y, wz.y, fmaf(h0.z, wz.z, fmaf(h0.w, wz.w, az[0]))));
      an[0] = fmaf(h0.x, wn.x, fmaf(h0.y, wn.y, fmaf(h0.z, wn.z, fmaf(h0.w, wn.w, an[0]))));
      ar[1] = fmaf(h1.x, wr.x, fmaf(h1.y, wr.y, fmaf(h1.z, wr.z, fmaf(h1.w, wr.w, ar[1]))));
      az[1] = fmaf(h1.x, wz.x, fmaf(h1.y, wz.y, fmaf(h1.z, wz.z, fmaf(h1.w, wz.w, az[1]))));
      an[1] = fmaf(h1.x, wn.x, fmaf(h1.y, wn.y, fmaf(h1.z, wn.z, fmaf(h1.w, wn.w, an[1]))));
    }
    __syncthreads();
  }

  const int u = u0 + ul;
  const float bhn = bhh[2 * SS + u];
#pragma unroll
  for (int e = 0; e < 2; ++e) {
    const int b = b0 + bp + e * 8;
    const size_t base = (size_t)(b * TT + t) * GG;
    const float xr = xg[base + u];
    const float xz = xg[base + SS + u];
    const float xn = xg[base + 2 * SS + u];
    const float r = 1.f / (1.f + expf(-(xr + ar[e])));
    const float z = 1.f / (1.f + expf(-(xz + az[e])));
    const float n = tanhf(xn + r * (an[e] + bhn));
    const float hold = hprev[(size_t)b * SS + u];
    hnext[(size_t)b * SS + u] = (1.f - z) * n + z * hold;
  }
}

// ---------------------------------------------------------------------------
// K3: out[b] = sigmoid(h[b] . W_out + b_out). One block per batch.
// ---------------------------------------------------------------------------
__global__ __launch_bounds__(256) void out_kernel(
    const float* __restrict__ h, const float* __restrict__ Wout,
    const float* __restrict__ bout, float* __restrict__ out) {
  const int b = blockIdx.x;
  const int tid = threadIdx.x;
  float s = 0.f;
#pragma unroll
  for (int i = 0; i < 4; ++i) {
    const int u = tid + i * 256;
    s = fmaf(h[(size_t)b * SS + u], Wout[u], s);
  }
#pragma unroll
  for (int off = 32; off; off >>= 1) s += __shfl_down(s, off);
  __shared__ float red[4];
  if ((tid & 63) == 0) red[tid >> 6] = s;
  __syncthreads();
  if (tid == 0) {
    const float tot = red[0] + red[1] + red[2] + red[3] + bout[0];
    out[b] = 1.f / (1.f + expf(-tot));
  }
}

__global__ void zero_kernel(float* __restrict__ p) {
  p[(size_t)blockIdx.x * 1024 + threadIdx.x] = 0.f;
}

// ---------------------------------------------------------------------------
extern "C" void kernel_launch(void* const* d_in, const int* in_sizes, int n_in,
                              void* d_out, int out_size, void* d_ws,
                              size_t ws_size, hipStream_t stream) {
  const float* batch = (const float*)d_in[0];  // [B,T,S]
  const float* W_ih = (const float*)d_in[1];   // [3S,S]
  const float* W_hh = (const float*)d_in[2];   // [3S,S]
  const float* b_ih = (const float*)d_in[3];   // [3S]
  const float* b_hh = (const float*)d_in[4];   // [3S]
  const float* W_out = (const float*)d_in[5];  // [1,S]
  const float* b_out = (const float*)d_in[6];  // [1]
  float* out = (float*)d_out;                  // [B]

  float* xg = (float*)d_ws;                        // B*T*3S floats (768 MB)
  float* hA = xg + (size_t)BB * TT * GG;           // B*S
  float* hB = hA + (size_t)BB * SS;                // B*S

  // h0 = 0 (ws is poisoned 0xAA before every launch)
  zero_kernel<<<BB, 1024, 0, stream>>>(hA);

  // Phase 1: big GEMM for all timesteps' input projections
  xgates_kernel<<<dim3(GG / 128, (BB * TT) / 128), 256, 0, stream>>>(
      batch, W_ih, b_ih, b_hh, xg);

  // Recurrence: 1024 sequential steps, double-buffered h
  for (int t = 0; t < TT; ++t) {
    const float* hp = (t & 1) ? hB : hA;
    float* hn = (t & 1) ? hA : hB;
    gru_step_kernel<<<128, 256, 0, stream>>>(hp, hn, W_hh, xg, b_hh, t);
  }
  // after t=1023 (odd), final h is in hA

  out_kernel<<<BB, 256, 0, stream>>>(hA, W_out, b_out, out);
}